// Round 2
// baseline (213.756 us; speedup 1.0000x reference)
//
#include <hip/hip_runtime.h>
#include <math.h>

#define Bn   4
#define CINc 64
#define Hh   160
#define Ww   160
#define Gg   8
#define HW   (Hh * Ww)      // 25600
#define COFF 216
#define NTILE 400           // 20x20 tiles per image

#define OROW 220            // offs row stride (ushorts) [fallback path]
#define VROW 200            // vbuf row stride (ushorts): staggered, 16B-aligned rows
#define OFFS_SZ (64 * OROW)
#define UNION_SZ 12800

typedef short bf16x8 __attribute__((ext_vector_type(8)));
typedef float f32x4  __attribute__((ext_vector_type(4)));

static __device__ __forceinline__ unsigned short f2bf(float f) {
    unsigned int u = __float_as_uint(f);
    u = (u + 0x7fffu + ((u >> 16) & 1u)) >> 16;
    return (unsigned short)u;
}
static __device__ __forceinline__ float bf2f(unsigned short s) {
    return __uint_as_float(((unsigned int)s) << 16);
}
static __device__ __forceinline__ float blo(unsigned int u) {
    return __uint_as_float(u << 16);
}
static __device__ __forceinline__ float bhi(unsigned int u) {
    return __uint_as_float(u & 0xffff0000u);
}

// ---------- Prep: transposes + weight repacks (1 launch) --------------------
#define WB 180
__global__ __launch_bounds__(256)
void prep_kernel(const float* __restrict__ feat, const float* __restrict__ x,
                 const float* __restrict__ w_off, const float* __restrict__ w_dcn,
                 unsigned short* __restrict__ featT, unsigned short* __restrict__ xG,
                 unsigned short* __restrict__ wofrag, unsigned short* __restrict__ wfrag) {
    const int blk = blockIdx.x;
    const int t = threadIdx.x;
    if (blk < 1280) {
        __shared__ float tile[CINc][161];
        const int isx = blk >= 640;
        const int rem = isx ? blk - 640 : blk;
        const int b = rem / Hh;
        const int h = rem % Hh;
        const float* src = isx ? x : feat;
        for (int i = t; i < CINc * (Ww / 4); i += 256) {
            int ci = i / (Ww / 4), w4 = i % (Ww / 4);
            float4 v = *(const float4*)(src + (((size_t)b * CINc + ci) * Hh + h) * Ww + w4 * 4);
            tile[ci][w4 * 4 + 0] = v.x; tile[ci][w4 * 4 + 1] = v.y;
            tile[ci][w4 * 4 + 2] = v.z; tile[ci][w4 * 4 + 3] = v.w;
        }
        __syncthreads();
        if (isx) {
            for (int i = t; i < CINc * Ww / 2; i += 256) {
                int g = i / (Ww * 4);
                int r = i % (Ww * 4);
                int w = r >> 2, cp = r & 3;
                unsigned int lo = f2bf(tile[g * 8 + 2 * cp][w]);
                unsigned int hi = f2bf(tile[g * 8 + 2 * cp + 1][w]);
                *(unsigned int*)(xG + (((size_t)b * Gg + g) * HW + h * Ww + w) * 8 + 2 * cp)
                    = lo | (hi << 16);
            }
        } else {
            for (int i = t; i < CINc * Ww / 2; i += 256) {
                int w = i / (CINc / 2), cp = i % (CINc / 2);
                unsigned int lo = f2bf(tile[2 * cp][w]);
                unsigned int hi = f2bf(tile[2 * cp + 1][w]);
                *(unsigned int*)(featT + (((size_t)b * Hh + h) * Ww + w) * CINc + 2 * cp)
                    = lo | (hi << 16);
            }
        }
    } else {
        for (int e = (blk - 1280) * 256 + t; e < 147456 + 36864; e += WB * 256) {
            if (e < 147456) {
                const int j    = e & 7;
                const int lane = (e >> 3) & 63;
                const int rest = e >> 9;
                const int mt = rest & 15;
                const int q  = rest >> 4;
                const int ks = q & 1;
                const int kp = q >> 1;
                const int co = mt * 16 + (lane & 15);
                const int ci = ks * 32 + (lane >> 4) * 8 + j;
                float v = (co < COFF) ? w_off[(size_t)co * 576 + ci * 9 + kp] : 0.f;
                wofrag[e] = f2bf(v);
            } else {
                const int e2   = e - 147456;
                const int j    = e2 & 7;
                const int lane = (e2 >> 3) & 63;
                const int mt   = (e2 >> 9) & 3;
                const int ks   = e2 >> 11;
                const int m = mt * 16 + (lane & 15);
                const int k = ks * 32 + (lane >> 4) * 8 + j;
                const int g = k / 72, r = k % 72;
                const int kk = r >> 3, cg = r & 7;
                const int ci = g * 8 + cg;
                wfrag[e2] = f2bf(w_dcn[((size_t)m * CINc + ci) * 9 + kk]);
            }
        }
    }
}

#define BLEND_J(out_, w00, w01, w10, w11, c00, c01, c10, c11) {            \
    float vl_ = (c00) * blo(w00) + (c01) * blo(w01)                        \
              + (c10) * blo(w10) + (c11) * blo(w11);                       \
    float vh_ = (c00) * bhi(w00) + (c01) * bhi(w01)                        \
              + (c10) * bhi(w10) + (c11) * bhi(w11);                       \
    asm("v_cvt_pk_bf16_f32 %0, %1, %2" : "=v"(out_) : "v"(vl_), "v"(vh_)); \
}

// ---------- Kernel A: conv -> global packed offsets -------------------------
// LDS = halo only (14.4 KB) -> high occupancy. Epilogue packs (dy,dx) as u32
// and mask as u16, tile-blocked [b][u][tile][64] for coalescing on both sides.
__global__ __launch_bounds__(256, 4)
void conv_off_kernel(const unsigned short* __restrict__ featT,
                     const unsigned short* __restrict__ wofrag,
                     const float* __restrict__ b_off,
                     unsigned int* __restrict__ offYX,
                     unsigned short* __restrict__ maskG) {
    __shared__ unsigned short halo[100 * 72];

    const int b  = blockIdx.z;
    const int h0 = blockIdx.y * 8;
    const int w0 = blockIdx.x * 8;
    const int tile = blockIdx.y * 20 + blockIdx.x;
    const int t  = threadIdx.x;
    const int wv   = t >> 6;
    const int lane = t & 63;
    const int n    = lane & 15;
    const int kg   = lane >> 4;

    // ---- stage halo: 100 pixels x 8 chunks of 8 bf16 ----
    for (int task = t; task < 800; task += 256) {
        const int pix = task >> 3, ch = task & 7;
        const int ry = pix / 10, rx = pix % 10;
        const int gh = h0 - 1 + ry, gw = w0 - 1 + rx;
        float4 v = make_float4(0.f, 0.f, 0.f, 0.f);
        if (gh >= 0 && gh < Hh && gw >= 0 && gw < Ww)
            v = *(const float4*)(featT + ((((size_t)b * Hh) + gh) * Ww + gw) * CINc + ch * 8);
        *(float4*)(halo + pix * 72 + ch * 8) = v;
    }
    __syncthreads();

    // ---- conv: M=256(pad of 216), N=64, K=576 ----
    const int bbase0 = (((n >> 3) * 10) + (n & 7)) * 72 + kg * 8;

    f32x4 cacc[4][4] = {};
    bf16x8 af[3][4];
    #pragma unroll
    for (int i = 0; i < 4; ++i)
        af[0][i] = *(const bf16x8*)(wofrag + (((size_t)0 * 16 + wv + 4 * i) * 64 + lane) * 8);
    #pragma unroll
    for (int i = 0; i < 4; ++i)
        af[1][i] = *(const bf16x8*)(wofrag + (((size_t)1 * 16 + wv + 4 * i) * 64 + lane) * 8);

    #pragma unroll
    for (int s = 0; s < 18; ++s) {
        if (s + 2 < 18) {
            #pragma unroll
            for (int i = 0; i < 4; ++i)
                af[(s + 2) % 3][i] = *(const bf16x8*)(wofrag +
                    (((size_t)(s + 2) * 16 + wv + 4 * i) * 64 + lane) * 8);
        }
        const int kp = s >> 1, ks = s & 1;
        const int ky = kp / 3, kx = kp % 3;
        #pragma unroll
        for (int nt = 0; nt < 4; ++nt) {
            const bf16x8 bfr = *(const bf16x8*)(halo + bbase0 + nt * 1440 +
                                                (ky * 10 + kx) * 72 + ks * 32);
            #pragma unroll
            for (int i = 0; i < 4; ++i)
                cacc[i][nt] = __builtin_amdgcn_mfma_f32_16x16x32_bf16(af[s % 3][i], bfr, cacc[i][nt], 0, 0, 0);
        }
    }

    // ---- epilogue -> global ----
    #pragma unroll
    for (int i = 0; i < 4; ++i) {
        const int mt = wv + 4 * i;
        #pragma unroll
        for (int nt = 0; nt < 4; ++nt) {
            const int p = nt * 16 + n;
            if (mt < 9) {
                // offsets: co = mt*16+kg*4+{0..3} all < 144; pairs (dy,dx)
                const int cob = mt * 16 + kg * 4;
                const int gkA = cob >> 1;
                const float v0 = cacc[i][nt][0] + b_off[cob + 0];
                const float v1 = cacc[i][nt][1] + b_off[cob + 1];
                const float v2 = cacc[i][nt][2] + b_off[cob + 2];
                const float v3 = cacc[i][nt][3] + b_off[cob + 3];
                unsigned int w01, w23;
                asm("v_cvt_pk_bf16_f32 %0, %1, %2" : "=v"(w01) : "v"(v0), "v"(v1));
                asm("v_cvt_pk_bf16_f32 %0, %1, %2" : "=v"(w23) : "v"(v2), "v"(v3));
                offYX[(((size_t)b * 72 + gkA)     * NTILE + tile) * 64 + p] = w01;
                offYX[(((size_t)b * 72 + gkA + 1) * NTILE + tile) * 64 + p] = w23;
            } else {
                #pragma unroll
                for (int r = 0; r < 4; ++r) {
                    const int co = mt * 16 + kg * 4 + r;
                    if (co < COFF) {
                        float v = cacc[i][nt][r] + b_off[co];
                        v = 1.f / (1.f + expf(-v));
                        maskG[(((size_t)b * 72 + (co - 144)) * NTILE + tile) * 64 + p] = f2bf(v);
                    }
                }
            }
        }
    }
}

// ---------- Kernel B: sample -> vbuf -> DCN GEMM ----------------------------
// LDS = vbuf only (25.6 KB) -> 4-6 blocks/CU for latency hiding.
__global__ __launch_bounds__(256, 4)
void dcn_sample_gemm(const unsigned int* __restrict__ offYX,
                     const unsigned short* __restrict__ maskG,
                     const unsigned short* __restrict__ xG,
                     const unsigned short* __restrict__ wfrag,
                     const float* __restrict__ b_dcn,
                     float* __restrict__ out) {
    __shared__ unsigned short vbuf[64 * VROW];

    const int b  = blockIdx.z;
    const int h0 = blockIdx.y * 8;
    const int w0 = blockIdx.x * 8;
    const int tile = blockIdx.y * 20 + blockIdx.x;
    const int t  = threadIdx.x;
    const int wv   = t >> 6;
    const int lane = t & 63;
    const int n    = lane & 15;
    const int kg   = lane >> 4;
    const int p_t = t & 63;
    const int h_s = h0 + (p_t >> 3);
    const int w_s = w0 + (p_t & 7);
    const float fh = (float)h_s;
    const float fw = (float)w_s;

    f32x4 dacc[4] = {};

    for (int c = 0; c < 3; ++c) {
        // -------- ISSUE phase: all 6 offset reads + 24 gathers --------------
        float cf[6][4];
        uint4 q[6][4];
        #pragma unroll
        for (int it = 0; it < 6; ++it) {
            const int u = __builtin_amdgcn_readfirstlane(c * 24 + wv + it * 4);
            const int g = u / 9;
            const int k = u % 9;

            const size_t uidx = (((size_t)b * 72 + u) * NTILE + tile) * 64 + p_t;
            const unsigned int yx = offYX[uidx];
            const float dy   = blo(yx);
            const float dx   = bhi(yx);
            const float mask = bf2f(maskG[uidx]);

            const float py  = fh + (float)(k / 3 - 1) + dy;
            const float pxx = fw + (float)(k % 3 - 1) + dx;
            const float y0f = floorf(py), x0f = floorf(pxx);
            const float ly = py - y0f, lx = pxx - x0f;
            const int y0 = (int)y0f, x0i = (int)x0f;
            const int y1 = y0 + 1,  x1  = x0i + 1;

            const float vy0 = (y0 >= 0 && y0 < Hh) ? 1.f : 0.f;
            const float vy1 = (y1 >= 0 && y1 < Hh) ? 1.f : 0.f;
            const float vx0 = (x0i >= 0 && x0i < Ww) ? 1.f : 0.f;
            const float vx1 = (x1 >= 0 && x1 < Ww) ? 1.f : 0.f;

            cf[it][0] = (1.f - ly) * (1.f - lx) * vy0 * vx0 * mask;
            cf[it][1] = (1.f - ly) * lx         * vy0 * vx1 * mask;
            cf[it][2] = ly         * (1.f - lx) * vy1 * vx0 * mask;
            cf[it][3] = ly         * lx         * vy1 * vx1 * mask;

            const int y0c = min(max(y0, 0), Hh - 1), y1c = min(max(y1, 0), Hh - 1);
            const int x0c = min(max(x0i, 0), Ww - 1), x1c = min(max(x1, 0), Ww - 1);

            const unsigned short* xb = xG + ((size_t)b * Gg + g) * HW * 8;
            q[it][0] = *(const uint4*)(xb + ((size_t)y0c * Ww + x0c) * 8);
            q[it][1] = *(const uint4*)(xb + ((size_t)y0c * Ww + x1c) * 8);
            q[it][2] = *(const uint4*)(xb + ((size_t)y1c * Ww + x0c) * 8);
            q[it][3] = *(const uint4*)(xb + ((size_t)y1c * Ww + x1c) * 8);
        }

        // -------- BLEND phase -----------------------------------------------
        #pragma unroll
        for (int it = 0; it < 6; ++it) {
            unsigned int rr0, rr1, rr2, rr3;
            BLEND_J(rr0, q[it][0].x, q[it][1].x, q[it][2].x, q[it][3].x,
                    cf[it][0], cf[it][1], cf[it][2], cf[it][3]);
            BLEND_J(rr1, q[it][0].y, q[it][1].y, q[it][2].y, q[it][3].y,
                    cf[it][0], cf[it][1], cf[it][2], cf[it][3]);
            BLEND_J(rr2, q[it][0].z, q[it][1].z, q[it][2].z, q[it][3].z,
                    cf[it][0], cf[it][1], cf[it][2], cf[it][3]);
            BLEND_J(rr3, q[it][0].w, q[it][1].w, q[it][2].w, q[it][3].w,
                    cf[it][0], cf[it][1], cf[it][2], cf[it][3]);
            uint4 res; res.x = rr0; res.y = rr1; res.z = rr2; res.w = rr3;
            *(uint4*)(vbuf + (size_t)p_t * VROW + (wv + it * 4) * 8) = res;
        }

        bf16x8 afr[6];
        #pragma unroll
        for (int s = 0; s < 6; ++s)
            afr[s] = *(const bf16x8*)(wfrag + (((size_t)(c * 6 + s) * 4 + wv) * 64 + lane) * 8);

        __syncthreads();

        #pragma unroll
        for (int s = 0; s < 6; ++s) {
            #pragma unroll
            for (int nt = 0; nt < 4; ++nt) {
                const bf16x8 bfr = *(const bf16x8*)(vbuf + (nt * 16 + n) * VROW + s * 32 + kg * 8);
                dacc[nt] = __builtin_amdgcn_mfma_f32_16x16x32_bf16(afr[s], bfr, dacc[nt], 0, 0, 0);
            }
        }
        __syncthreads();
    }

    #pragma unroll
    for (int nt = 0; nt < 4; ++nt) {
        const int p = nt * 16 + n;
        const int h = h0 + (p >> 3);
        const int w = w0 + (p & 7);
        #pragma unroll
        for (int r = 0; r < 4; ++r) {
            const int o = wv * 16 + kg * 4 + r;
            out[(((size_t)b * CINc + o) * HW) + h * Ww + w] = dacc[nt][r] + b_dcn[o];
        }
    }
}

// ---------- Fallback: round-1 fused kernel (small workspace) ----------------
__global__ __launch_bounds__(256, 3)
void dcnpack_fused(const unsigned short* __restrict__ featT,
                   const unsigned short* __restrict__ xG,
                   const unsigned short* __restrict__ wofrag,
                   const unsigned short* __restrict__ wfrag,
                   const float* __restrict__ b_off,
                   const float* __restrict__ b_dcn,
                   float* __restrict__ out) {
    __shared__ unsigned short smem[OFFS_SZ + UNION_SZ];
    unsigned short* offs = smem;
    unsigned short* halo = smem + OFFS_SZ;
    unsigned short* vbuf = smem + OFFS_SZ;

    const int b  = blockIdx.z;
    const int h0 = blockIdx.y * 8;
    const int w0 = blockIdx.x * 8;
    const int t  = threadIdx.x;
    const int wv   = t >> 6;
    const int lane = t & 63;
    const int n    = lane & 15;
    const int kg   = lane >> 4;

    for (int task = t; task < 800; task += 256) {
        const int pix = task >> 3, ch = task & 7;
        const int ry = pix / 10, rx = pix % 10;
        const int gh = h0 - 1 + ry, gw = w0 - 1 + rx;
        float4 v = make_float4(0.f, 0.f, 0.f, 0.f);
        if (gh >= 0 && gh < Hh && gw >= 0 && gw < Ww)
            v = *(const float4*)(featT + ((((size_t)b * Hh) + gh) * Ww + gw) * CINc + ch * 8);
        *(float4*)(halo + pix * 72 + ch * 8) = v;
    }
    __syncthreads();

    const int bbase0 = (((n >> 3) * 10) + (n & 7)) * 72 + kg * 8;

    f32x4 cacc[4][4] = {};
    bf16x8 af[3][4];
    #pragma unroll
    for (int i = 0; i < 4; ++i)
        af[0][i] = *(const bf16x8*)(wofrag + (((size_t)0 * 16 + wv + 4 * i) * 64 + lane) * 8);
    #pragma unroll
    for (int i = 0; i < 4; ++i)
        af[1][i] = *(const bf16x8*)(wofrag + (((size_t)1 * 16 + wv + 4 * i) * 64 + lane) * 8);

    #pragma unroll
    for (int s = 0; s < 18; ++s) {
        if (s + 2 < 18) {
            #pragma unroll
            for (int i = 0; i < 4; ++i)
                af[(s + 2) % 3][i] = *(const bf16x8*)(wofrag +
                    (((size_t)(s + 2) * 16 + wv + 4 * i) * 64 + lane) * 8);
        }
        const int kp = s >> 1, ks = s & 1;
        const int ky = kp / 3, kx = kp % 3;
        #pragma unroll
        for (int nt = 0; nt < 4; ++nt) {
            const bf16x8 bfr = *(const bf16x8*)(halo + bbase0 + nt * 1440 +
                                                (ky * 10 + kx) * 72 + ks * 32);
            #pragma unroll
            for (int i = 0; i < 4; ++i)
                cacc[i][nt] = __builtin_amdgcn_mfma_f32_16x16x32_bf16(af[s % 3][i], bfr, cacc[i][nt], 0, 0, 0);
        }
    }

    #pragma unroll
    for (int i = 0; i < 4; ++i) {
        const int mt = wv + 4 * i;
        #pragma unroll
        for (int r = 0; r < 4; ++r) {
            const int co = mt * 16 + kg * 4 + r;
            if (co < COFF) {
                const float bias = b_off[co];
                const int ismask = (co >= 144);
                const int gk = ismask ? (co - 144) : (co >> 1);
                const int type = ismask ? 2 : (co & 1);
                #pragma unroll
                for (int nt = 0; nt < 4; ++nt) {
                    const int p = nt * 16 + n;
                    float v = cacc[i][nt][r] + bias;
                    if (ismask) v = 1.f / (1.f + expf(-v));
                    offs[p * OROW + gk * 3 + type] = f2bf(v);
                }
            }
        }
    }
    __syncthreads();

    f32x4 dacc[4] = {};
    const int p_t = t & 63;
    const int h_s = h0 + (p_t >> 3);
    const int w_s = w0 + (p_t & 7);

    for (int c = 0; c < 3; ++c) {
        float cf[6][4];
        uint4 q[6][4];
        #pragma unroll
        for (int it = 0; it < 6; ++it) {
            const int u = c * 24 + wv + it * 4;
            const int g = u / 9;
            const int k = u % 9;

            const float dy   = bf2f(offs[p_t * OROW + u * 3 + 0]);
            const float dx   = bf2f(offs[p_t * OROW + u * 3 + 1]);
            const float mask = bf2f(offs[p_t * OROW + u * 3 + 2]);

            const float py  = (float)h_s + (float)(k / 3 - 1) + dy;
            const float pxx = (float)w_s + (float)(k % 3 - 1) + dx;
            const float y0f = floorf(py), x0f = floorf(pxx);
            const float ly = py - y0f, lx = pxx - x0f;
            const int y0 = (int)y0f, x0i = (int)x0f;
            const int y1 = y0 + 1,  x1  = x0i + 1;

            const float vy0 = (y0 >= 0 && y0 < Hh) ? 1.f : 0.f;
            const float vy1 = (y1 >= 0 && y1 < Hh) ? 1.f : 0.f;
            const float vx0 = (x0i >= 0 && x0i < Ww) ? 1.f : 0.f;
            const float vx1 = (x1 >= 0 && x1 < Ww) ? 1.f : 0.f;

            cf[it][0] = (1.f - ly) * (1.f - lx) * vy0 * vx0 * mask;
            cf[it][1] = (1.f - ly) * lx         * vy0 * vx1 * mask;
            cf[it][2] = ly         * (1.f - lx) * vy1 * vx0 * mask;
            cf[it][3] = ly         * lx         * vy1 * vx1 * mask;

            const int y0c = min(max(y0, 0), Hh - 1), y1c = min(max(y1, 0), Hh - 1);
            const int x0c = min(max(x0i, 0), Ww - 1), x1c = min(max(x1, 0), Ww - 1);

            const unsigned short* xb = xG + ((size_t)b * Gg + g) * HW * 8;
            q[it][0] = *(const uint4*)(xb + ((size_t)y0c * Ww + x0c) * 8);
            q[it][1] = *(const uint4*)(xb + ((size_t)y0c * Ww + x1c) * 8);
            q[it][2] = *(const uint4*)(xb + ((size_t)y1c * Ww + x0c) * 8);
            q[it][3] = *(const uint4*)(xb + ((size_t)y1c * Ww + x1c) * 8);
        }

        #pragma unroll
        for (int it = 0; it < 6; ++it) {
            unsigned int rr0, rr1, rr2, rr3;
            BLEND_J(rr0, q[it][0].x, q[it][1].x, q[it][2].x, q[it][3].x,
                    cf[it][0], cf[it][1], cf[it][2], cf[it][3]);
            BLEND_J(rr1, q[it][0].y, q[it][1].y, q[it][2].y, q[it][3].y,
                    cf[it][0], cf[it][1], cf[it][2], cf[it][3]);
            BLEND_J(rr2, q[it][0].z, q[it][1].z, q[it][2].z, q[it][3].z,
                    cf[it][0], cf[it][1], cf[it][2], cf[it][3]);
            BLEND_J(rr3, q[it][0].w, q[it][1].w, q[it][2].w, q[it][3].w,
                    cf[it][0], cf[it][1], cf[it][2], cf[it][3]);
            uint4 res; res.x = rr0; res.y = rr1; res.z = rr2; res.w = rr3;
            *(uint4*)(vbuf + (size_t)p_t * VROW + (wv + it * 4) * 8) = res;
        }

        bf16x8 afr[6];
        #pragma unroll
        for (int s = 0; s < 6; ++s)
            afr[s] = *(const bf16x8*)(wfrag + (((size_t)(c * 6 + s) * 4 + wv) * 64 + lane) * 8);

        __syncthreads();

        #pragma unroll
        for (int s = 0; s < 6; ++s) {
            #pragma unroll
            for (int nt = 0; nt < 4; ++nt) {
                const bf16x8 bfr = *(const bf16x8*)(vbuf + (nt * 16 + n) * VROW + s * 32 + kg * 8);
                dacc[nt] = __builtin_amdgcn_mfma_f32_16x16x32_bf16(afr[s], bfr, dacc[nt], 0, 0, 0);
            }
        }
        __syncthreads();
    }

    #pragma unroll
    for (int nt = 0; nt < 4; ++nt) {
        const int p = nt * 16 + n;
        const int h = h0 + (p >> 3);
        const int w = w0 + (p & 7);
        #pragma unroll
        for (int r = 0; r < 4; ++r) {
            const int o = wv * 16 + kg * 4 + r;
            out[(((size_t)b * CINc + o) * HW) + h * Ww + w] = dacc[nt][r] + b_dcn[o];
        }
    }
}

extern "C" void kernel_launch(void* const* d_in, const int* in_sizes, int n_in,
                              void* d_out, int out_size, void* d_ws, size_t ws_size,
                              hipStream_t stream) {
    const float* x     = (const float*)d_in[0];
    const float* feat  = (const float*)d_in[1];
    const float* w_off = (const float*)d_in[2];
    const float* b_off = (const float*)d_in[3];
    const float* w_dcn = (const float*)d_in[4];
    const float* b_dcn = (const float*)d_in[5];
    float* out = (float*)d_out;

    const size_t FEATT_E = (size_t)Bn * HW * CINc;   // 6,553,600 ushorts each
    const size_t OFF_E   = (size_t)Bn * 72 * HW;     // 7,372,800 entries

    // split layout: [offYX u32][featT][xG][wofrag][wfrag][maskG] = ~70.8 MB
    const size_t need = OFF_E * 4 + FEATT_E * 2 * 2 + 147456 * 2 + 36864 * 2 + OFF_E * 2;

    if (ws_size >= need) {
        unsigned int*   offYX  = (unsigned int*)d_ws;
        unsigned short* featT  = (unsigned short*)(offYX + OFF_E);
        unsigned short* xG     = featT + FEATT_E;
        unsigned short* wofrag = xG + FEATT_E;
        unsigned short* wfrag  = wofrag + (size_t)147456;
        unsigned short* maskG  = wfrag + (size_t)36864;

        prep_kernel<<<dim3(1280 + WB), 256, 0, stream>>>(
            feat, x, w_off, w_dcn, featT, xG, wofrag, wfrag);
        conv_off_kernel<<<dim3(Ww / 8, Hh / 8, Bn), 256, 0, stream>>>(
            featT, wofrag, b_off, offYX, maskG);
        dcn_sample_gemm<<<dim3(Ww / 8, Hh / 8, Bn), 256, 0, stream>>>(
            offYX, maskG, xG, wfrag, b_dcn, out);
    } else {
        unsigned short* featT  = (unsigned short*)d_ws;
        unsigned short* xG     = featT + FEATT_E;
        unsigned short* wofrag = xG + FEATT_E;
        unsigned short* wfrag  = wofrag + (size_t)147456;

        prep_kernel<<<dim3(1280 + WB), 256, 0, stream>>>(
            feat, x, w_off, w_dcn, featT, xG, wofrag, wfrag);
        dcnpack_fused<<<dim3(Ww / 8, Hh / 8, Bn), 256, 0, stream>>>(
            featT, xG, wofrag, wfrag, b_off, b_dcn, out);
    }
}

// Round 3
// 194.553 us; speedup vs baseline: 1.0987x; 1.0987x over previous
//
#include <hip/hip_runtime.h>
#include <math.h>

#define Bn   4
#define CINc 64
#define Hh   160
#define Ww   160
#define Gg   8
#define HW   (Hh * Ww)      // 25600
#define COFF 216

#define OROW 220            // offs row stride (ushorts): conflict-free stagger
#define VROW 200            // vbuf row stride (ushorts): 16B-aligned rows
#define OFFS_SZ (64 * OROW)
#define UNION_SZ 12800
// fused smem = 26880 ushorts = 53760 B -> 3 blocks/CU

typedef short bf16x8 __attribute__((ext_vector_type(8)));
typedef float f32x4  __attribute__((ext_vector_type(4)));

static __device__ __forceinline__ unsigned short f2bf(float f) {
    unsigned int u = __float_as_uint(f);
    u = (u + 0x7fffu + ((u >> 16) & 1u)) >> 16;
    return (unsigned short)u;
}
static __device__ __forceinline__ float bf2f(unsigned short s) {
    return __uint_as_float(((unsigned int)s) << 16);
}
static __device__ __forceinline__ float blo(unsigned int u) {
    return __uint_as_float(u << 16);
}
static __device__ __forceinline__ float bhi(unsigned int u) {
    return __uint_as_float(u & 0xffff0000u);
}

// ---------- Prep v2: bf16-LDS transposes (7 blocks/CU) + weight repacks -----
// blocks [0,640): feat -> featT [b][pix][64] ; [640,1280): x -> xG [b][g][pix][8]
// [1280,1280+WB): grid-stride weight repacks
#define WB 180
__global__ __launch_bounds__(256)
void prep_kernel(const float* __restrict__ feat, const float* __restrict__ x,
                 const float* __restrict__ w_off, const float* __restrict__ w_dcn,
                 unsigned short* __restrict__ featT, unsigned short* __restrict__ xG,
                 unsigned short* __restrict__ wofrag, unsigned short* __restrict__ wfrag) {
    const int blk = blockIdx.x;
    const int t = threadIdx.x;
    if (blk < 1280) {
        // bf16 tile: 64 x 170 ushorts = 21760 B  -> 7 blocks/CU
        __shared__ unsigned short tileu[CINc][170];
        const int isx = blk >= 640;
        const int rem = isx ? blk - 640 : blk;
        const int b = rem / Hh;
        const int h = rem % Hh;
        const float* src = isx ? x : feat;
        // load 2560 float4, convert to bf16 pairs, 2x b32 LDS stores each
        #pragma unroll
        for (int it = 0; it < 10; ++it) {
            const int i = t + it * 256;
            const int ci = i / 40, w4 = i % 40;
            const float4 v = *(const float4*)(src + (((size_t)b * CINc + ci) * Hh + h) * Ww + w4 * 4);
            unsigned int p01, p23;
            asm("v_cvt_pk_bf16_f32 %0, %1, %2" : "=v"(p01) : "v"(v.x), "v"(v.y));
            asm("v_cvt_pk_bf16_f32 %0, %1, %2" : "=v"(p23) : "v"(v.z), "v"(v.w));
            *(unsigned int*)&tileu[ci][w4 * 4]     = p01;
            *(unsigned int*)&tileu[ci][w4 * 4 + 2] = p23;
        }
        __syncthreads();
        if (isx) {
            // xG: [b][g][pix][8 cg] ; lanes -> contiguous 256B u32 stores
            #pragma unroll
            for (int it = 0; it < 20; ++it) {
                const int i = t + it * 256;            // < 5120
                const int g = i / 640, r = i % 640;
                const int w = r >> 2, cp = r & 3;
                const unsigned int lo = tileu[g * 8 + 2 * cp][w];
                const unsigned int hi = tileu[g * 8 + 2 * cp + 1][w];
                ((unsigned int*)xG)[(((size_t)b * Gg + g) * HW + h * Ww + w) * 4 + cp]
                    = lo | (hi << 16);
            }
        } else {
            // featT: [b][pix][64 ci] ; lanes -> contiguous 256B u32 stores
            #pragma unroll
            for (int it = 0; it < 20; ++it) {
                const int i = t + it * 256;            // < 5120
                const int w = i >> 5, cp = i & 31;
                const unsigned int lo = tileu[2 * cp][w];
                const unsigned int hi = tileu[2 * cp + 1][w];
                ((unsigned int*)featT)[(((size_t)b * Hh + h) * Ww + w) * 32 + cp]
                    = lo | (hi << 16);
            }
        }
    } else {
        for (int e = (blk - 1280) * 256 + t; e < 147456 + 36864; e += WB * 256) {
            if (e < 147456) {
                // wofrag[kp(9)][ks(2)][mt(16)][lane(64)][j(8)]
                const int j    = e & 7;
                const int lane = (e >> 3) & 63;
                const int rest = e >> 9;
                const int mt = rest & 15;
                const int q  = rest >> 4;
                const int ks = q & 1;
                const int kp = q >> 1;
                const int co = mt * 16 + (lane & 15);
                const int ci = ks * 32 + (lane >> 4) * 8 + j;
                float v = (co < COFF) ? w_off[(size_t)co * 576 + ci * 9 + kp] : 0.f;
                wofrag[e] = f2bf(v);
            } else {
                // wfrag[ks(18)][mt(4)][lane(64)][j(8)], permuted K = g*72+kk*8+cg
                const int e2   = e - 147456;
                const int j    = e2 & 7;
                const int lane = (e2 >> 3) & 63;
                const int mt   = (e2 >> 9) & 3;
                const int ks   = e2 >> 11;
                const int m = mt * 16 + (lane & 15);
                const int k = ks * 32 + (lane >> 4) * 8 + j;
                const int g = k / 72, r = k % 72;
                const int kk = r >> 3, cg = r & 7;
                const int ci = g * 8 + cg;
                wfrag[e2] = f2bf(w_dcn[((size_t)m * CINc + ci) * 9 + kk]);
            }
        }
    }
}

// blend one dword-lane pair with packed bf16 convert (RNE, same as f2bf)
#define BLEND_J(out_, w00, w01, w10, w11, c00, c01, c10, c11) {            \
    float vl_ = (c00) * blo(w00) + (c01) * blo(w01)                        \
              + (c10) * blo(w10) + (c11) * blo(w11);                       \
    float vh_ = (c00) * bhi(w00) + (c01) * bhi(w01)                        \
              + (c10) * bhi(w10) + (c11) * bhi(w11);                       \
    asm("v_cvt_pk_bf16_f32 %0, %1, %2" : "=v"(out_) : "v"(vl_), "v"(vh_)); \
}

// ---------- Fused kernel: conv -> LDS offsets -> sample -> DCN GEMM ---------
// block = 8x8 pixel tile, 256 threads (4 waves). 1600 blocks.
__global__ __launch_bounds__(256, 3)
void dcnpack_fused(const unsigned short* __restrict__ featT,
                   const unsigned short* __restrict__ xG,
                   const unsigned short* __restrict__ wofrag,
                   const unsigned short* __restrict__ wfrag,
                   const float* __restrict__ b_off,
                   const float* __restrict__ b_dcn,
                   float* __restrict__ out) {
    __shared__ unsigned short smem[OFFS_SZ + UNION_SZ];
    unsigned short* offs = smem;                // [64 pix][OROW]: gk*3 + {dy,dx,mask}
    unsigned short* halo = smem + OFFS_SZ;      // [ry(10)][rx(10)][72] (conv phase)
    unsigned short* vbuf = smem + OFFS_SZ;      // [64 pix][VROW]     (dcn phase)

    const int b  = blockIdx.z;
    const int h0 = blockIdx.y * 8;
    const int w0 = blockIdx.x * 8;
    const int t  = threadIdx.x;
    const int wv   = t >> 6;
    const int lane = t & 63;
    const int n    = lane & 15;
    const int kg   = lane >> 4;

    // ---- stage halo: 100 pixels x 8 chunks of 8 bf16 ----
    for (int task = t; task < 800; task += 256) {
        const int pix = task >> 3, ch = task & 7;
        const int ry = pix / 10, rx = pix % 10;
        const int gh = h0 - 1 + ry, gw = w0 - 1 + rx;
        float4 v = make_float4(0.f, 0.f, 0.f, 0.f);
        if (gh >= 0 && gh < Hh && gw >= 0 && gw < Ww)
            v = *(const float4*)(featT + ((((size_t)b * Hh) + gh) * Ww + gw) * CINc + ch * 8);
        *(float4*)(halo + pix * 72 + ch * 8) = v;
    }
    __syncthreads();

    // ---- conv phase: M=256(pad of 216), N=64, K=576 ----
    const int bbase0 = (((n >> 3) * 10) + (n & 7)) * 72 + kg * 8;

    f32x4 cacc[4][4] = {};
    bf16x8 af[3][4];
    #pragma unroll
    for (int i = 0; i < 4; ++i)
        af[0][i] = *(const bf16x8*)(wofrag + (((size_t)0 * 16 + wv + 4 * i) * 64 + lane) * 8);
    #pragma unroll
    for (int i = 0; i < 4; ++i)
        af[1][i] = *(const bf16x8*)(wofrag + (((size_t)1 * 16 + wv + 4 * i) * 64 + lane) * 8);

    #pragma unroll
    for (int s = 0; s < 18; ++s) {
        if (s + 2 < 18) {
            #pragma unroll
            for (int i = 0; i < 4; ++i)
                af[(s + 2) % 3][i] = *(const bf16x8*)(wofrag +
                    (((size_t)(s + 2) * 16 + wv + 4 * i) * 64 + lane) * 8);
        }
        const int kp = s >> 1, ks = s & 1;
        const int ky = kp / 3, kx = kp % 3;
        __builtin_amdgcn_s_setprio(1);
        #pragma unroll
        for (int nt = 0; nt < 4; ++nt) {
            const bf16x8 bfr = *(const bf16x8*)(halo + bbase0 + nt * 1440 +
                                                (ky * 10 + kx) * 72 + ks * 32);
            #pragma unroll
            for (int i = 0; i < 4; ++i)
                cacc[i][nt] = __builtin_amdgcn_mfma_f32_16x16x32_bf16(af[s % 3][i], bfr, cacc[i][nt], 0, 0, 0);
        }
        __builtin_amdgcn_s_setprio(0);
    }

    // ---- conv epilogue: bias (+sigmoid for mask) -> offs LDS ----
    #pragma unroll
    for (int i = 0; i < 4; ++i) {
        const int mt = wv + 4 * i;
        #pragma unroll
        for (int r = 0; r < 4; ++r) {
            const int co = mt * 16 + kg * 4 + r;
            if (co < COFF) {
                const float bias = b_off[co];
                const int ismask = (co >= 144);
                const int gk = ismask ? (co - 144) : (co >> 1);
                const int type = ismask ? 2 : (co & 1);
                #pragma unroll
                for (int nt = 0; nt < 4; ++nt) {
                    const int p = nt * 16 + n;
                    float v = cacc[i][nt][r] + bias;
                    if (ismask) v = 1.f / (1.f + expf(-v));
                    offs[p * OROW + gk * 3 + type] = f2bf(v);
                }
            }
        }
    }
    __syncthreads();

    // ---- DCN: 3 K-windows of 192 (24 (g,k)-units); sample -> GEMM ----
    f32x4 dacc[4] = {};
    const int p_t = t & 63;
    const int h_s = h0 + (p_t >> 3);
    const int w_s = w0 + (p_t & 7);

    for (int c = 0; c < 3; ++c) {
        // -------- ISSUE phase: all offset reads + 24 gathers in flight ------
        float cf[6][4];
        uint4 q[6][4];
        #pragma unroll
        for (int it = 0; it < 6; ++it) {
            const int u = c * 24 + wv + it * 4;
            const int g = u / 9;
            const int k = u % 9;

            const float dy   = bf2f(offs[p_t * OROW + u * 3 + 0]);
            const float dx   = bf2f(offs[p_t * OROW + u * 3 + 1]);
            const float mask = bf2f(offs[p_t * OROW + u * 3 + 2]);

            const float py  = (float)h_s + (float)(k / 3 - 1) + dy;
            const float pxx = (float)w_s + (float)(k % 3 - 1) + dx;
            const float y0f = floorf(py), x0f = floorf(pxx);
            const float ly = py - y0f, lx = pxx - x0f;
            const int y0 = (int)y0f, x0i = (int)x0f;
            const int y1 = y0 + 1,  x1  = x0i + 1;

            const float vy0 = (y0 >= 0 && y0 < Hh) ? 1.f : 0.f;
            const float vy1 = (y1 >= 0 && y1 < Hh) ? 1.f : 0.f;
            const float vx0 = (x0i >= 0 && x0i < Ww) ? 1.f : 0.f;
            const float vx1 = (x1 >= 0 && x1 < Ww) ? 1.f : 0.f;

            cf[it][0] = (1.f - ly) * (1.f - lx) * vy0 * vx0 * mask;
            cf[it][1] = (1.f - ly) * lx         * vy0 * vx1 * mask;
            cf[it][2] = ly         * (1.f - lx) * vy1 * vx0 * mask;
            cf[it][3] = ly         * lx         * vy1 * vx1 * mask;

            const int y0c = min(max(y0, 0), Hh - 1), y1c = min(max(y1, 0), Hh - 1);
            const int x0c = min(max(x0i, 0), Ww - 1), x1c = min(max(x1, 0), Ww - 1);

            const unsigned short* xb = xG + ((size_t)b * Gg + g) * HW * 8;
            q[it][0] = *(const uint4*)(xb + ((size_t)y0c * Ww + x0c) * 8);
            q[it][1] = *(const uint4*)(xb + ((size_t)y0c * Ww + x1c) * 8);
            q[it][2] = *(const uint4*)(xb + ((size_t)y1c * Ww + x0c) * 8);
            q[it][3] = *(const uint4*)(xb + ((size_t)y1c * Ww + x1c) * 8);
        }

        // -------- BLEND phase: consume gathers, write vbuf ------------------
        #pragma unroll
        for (int it = 0; it < 6; ++it) {
            unsigned int rr0, rr1, rr2, rr3;
            BLEND_J(rr0, q[it][0].x, q[it][1].x, q[it][2].x, q[it][3].x,
                    cf[it][0], cf[it][1], cf[it][2], cf[it][3]);
            BLEND_J(rr1, q[it][0].y, q[it][1].y, q[it][2].y, q[it][3].y,
                    cf[it][0], cf[it][1], cf[it][2], cf[it][3]);
            BLEND_J(rr2, q[it][0].z, q[it][1].z, q[it][2].z, q[it][3].z,
                    cf[it][0], cf[it][1], cf[it][2], cf[it][3]);
            BLEND_J(rr3, q[it][0].w, q[it][1].w, q[it][2].w, q[it][3].w,
                    cf[it][0], cf[it][1], cf[it][2], cf[it][3]);
            uint4 res; res.x = rr0; res.y = rr1; res.z = rr2; res.w = rr3;
            *(uint4*)(vbuf + (size_t)p_t * VROW + (wv + it * 4) * 8) = res;
        }

        // prefetch this window's 6 A-fragments (global, L2) before the barrier
        bf16x8 afr[6];
        #pragma unroll
        for (int s = 0; s < 6; ++s)
            afr[s] = *(const bf16x8*)(wfrag + (((size_t)(c * 6 + s) * 4 + wv) * 64 + lane) * 8);

        __syncthreads();

        // GEMM over this window: 6 k-steps
        __builtin_amdgcn_s_setprio(1);
        #pragma unroll
        for (int s = 0; s < 6; ++s) {
            #pragma unroll
            for (int nt = 0; nt < 4; ++nt) {
                const bf16x8 bfr = *(const bf16x8*)(vbuf + (nt * 16 + n) * VROW + s * 32 + kg * 8);
                dacc[nt] = __builtin_amdgcn_mfma_f32_16x16x32_bf16(afr[s], bfr, dacc[nt], 0, 0, 0);
            }
        }
        __builtin_amdgcn_s_setprio(0);
        __syncthreads();
    }

    // ---- final epilogue ----
    #pragma unroll
    for (int nt = 0; nt < 4; ++nt) {
        const int p = nt * 16 + n;
        const int h = h0 + (p >> 3);
        const int w = w0 + (p & 7);
        #pragma unroll
        for (int r = 0; r < 4; ++r) {
            const int o = wv * 16 + kg * 4 + r;
            out[(((size_t)b * CINc + o) * HW) + h * Ww + w] = dacc[nt][r] + b_dcn[o];
        }
    }
}

extern "C" void kernel_launch(void* const* d_in, const int* in_sizes, int n_in,
                              void* d_out, int out_size, void* d_ws, size_t ws_size,
                              hipStream_t stream) {
    const float* x     = (const float*)d_in[0];
    const float* feat  = (const float*)d_in[1];
    const float* w_off = (const float*)d_in[2];
    const float* b_off = (const float*)d_in[3];
    const float* w_dcn = (const float*)d_in[4];
    const float* b_dcn = (const float*)d_in[5];
    float* out = (float*)d_out;

    // ws layout (ushort elements): featT, xG, wofrag, wfrag  (~26.6 MB)
    unsigned short* featT  = (unsigned short*)d_ws;                // 6,553,600
    unsigned short* xG     = featT + (size_t)Bn * HW * CINc;       // 6,553,600
    unsigned short* wofrag = xG + (size_t)Bn * HW * CINc;          // 147,456
    unsigned short* wfrag  = wofrag + (size_t)147456;              // 36,864

    prep_kernel<<<dim3(1280 + WB), 256, 0, stream>>>(
        feat, x, w_off, w_dcn, featT, xG, wofrag, wfrag);
    dcnpack_fused<<<dim3(Ww / 8, Hh / 8, Bn), 256, 0, stream>>>(
        featT, xG, wofrag, wfrag, b_off, b_dcn, out);
}

// Round 4
// 186.111 us; speedup vs baseline: 1.1485x; 1.0454x over previous
//
#include <hip/hip_runtime.h>
#include <math.h>

#define Bn   4
#define CINc 64
#define Hh   160
#define Ww   160
#define Gg   8
#define HW   (Hh * Ww)      // 25600
#define COFF 216

#define OROW 220            // offs row stride (ushorts): conflict-free stagger
#define VROW 200            // vbuf row stride (ushorts): 16B-aligned rows
#define OFFS_SZ (64 * OROW)
#define UNION_SZ 12800
// fused smem = 26880 ushorts = 53760 B -> 3 blocks/CU

typedef short bf16x8 __attribute__((ext_vector_type(8)));
typedef float f32x4  __attribute__((ext_vector_type(4)));

static __device__ __forceinline__ unsigned short f2bf(float f) {
    unsigned int u = __float_as_uint(f);
    u = (u + 0x7fffu + ((u >> 16) & 1u)) >> 16;
    return (unsigned short)u;
}
static __device__ __forceinline__ float bf2f(unsigned short s) {
    return __uint_as_float(((unsigned int)s) << 16);
}
static __device__ __forceinline__ float blo(unsigned int u) {
    return __uint_as_float(u << 16);
}
static __device__ __forceinline__ float bhi(unsigned int u) {
    return __uint_as_float(u & 0xffff0000u);
}

// ---------- Prep v3: bf16-LDS transpose (7 blocks/CU) + uint4 stores --------
// blocks [0,640): feat -> featT [b][pix][64] ; [640,1280): x -> xG [b][g][pix][8]
// [1280,1280+WB): grid-stride weight repacks
#define WB 180
__global__ __launch_bounds__(256)
void prep_kernel(const float* __restrict__ feat, const float* __restrict__ x,
                 const float* __restrict__ w_off, const float* __restrict__ w_dcn,
                 unsigned short* __restrict__ featT, unsigned short* __restrict__ xG,
                 unsigned short* __restrict__ wofrag, unsigned short* __restrict__ wfrag) {
    const int blk = blockIdx.x;
    const int t = threadIdx.x;
    if (blk < 1280) {
        // bf16 tile: 64 x 170 ushorts = 21760 B  -> 7 blocks/CU
        __shared__ unsigned short tileu[CINc][170];
        const int isx = blk >= 640;
        const int rem = isx ? blk - 640 : blk;
        const int b = rem / Hh;
        const int h = rem % Hh;
        const float* src = isx ? x : feat;
        // load 2560 float4, convert to bf16 pairs, 2x b32 LDS stores each
        #pragma unroll
        for (int it = 0; it < 10; ++it) {
            const int i = t + it * 256;
            const int ci = i / 40, w4 = i % 40;
            const float4 v = *(const float4*)(src + (((size_t)b * CINc + ci) * Hh + h) * Ww + w4 * 4);
            unsigned int p01, p23;
            asm("v_cvt_pk_bf16_f32 %0, %1, %2" : "=v"(p01) : "v"(v.x), "v"(v.y));
            asm("v_cvt_pk_bf16_f32 %0, %1, %2" : "=v"(p23) : "v"(v.z), "v"(v.w));
            *(unsigned int*)&tileu[ci][w4 * 4]     = p01;
            *(unsigned int*)&tileu[ci][w4 * 4 + 2] = p23;
        }
        __syncthreads();
        if (isx) {
            // xG: [b][g][pix][8 cg] ; one uint4 (= whole 8-channel pixel) per task
            #pragma unroll
            for (int it = 0; it < 5; ++it) {
                const int i = t + it * 256;            // < 1280
                const int g = i / 160, w = i % 160;    // lanes -> consecutive w
                unsigned int d0, d1, d2, d3;
                d0 = (unsigned int)tileu[g * 8 + 0][w] | ((unsigned int)tileu[g * 8 + 1][w] << 16);
                d1 = (unsigned int)tileu[g * 8 + 2][w] | ((unsigned int)tileu[g * 8 + 3][w] << 16);
                d2 = (unsigned int)tileu[g * 8 + 4][w] | ((unsigned int)tileu[g * 8 + 5][w] << 16);
                d3 = (unsigned int)tileu[g * 8 + 6][w] | ((unsigned int)tileu[g * 8 + 7][w] << 16);
                uint4 res; res.x = d0; res.y = d1; res.z = d2; res.w = d3;
                ((uint4*)xG)[((size_t)b * Gg + g) * HW + h * Ww + w] = res;
            }
        } else {
            // featT: [b][pix][64 ci] ; one uint4 (8-channel chunk) per task
            #pragma unroll
            for (int it = 0; it < 5; ++it) {
                const int i = t + it * 256;            // < 1280
                const int w = i >> 3, cj = i & 7;      // lanes -> consecutive uint4
                unsigned int d0, d1, d2, d3;
                d0 = (unsigned int)tileu[cj * 8 + 0][w] | ((unsigned int)tileu[cj * 8 + 1][w] << 16);
                d1 = (unsigned int)tileu[cj * 8 + 2][w] | ((unsigned int)tileu[cj * 8 + 3][w] << 16);
                d2 = (unsigned int)tileu[cj * 8 + 4][w] | ((unsigned int)tileu[cj * 8 + 5][w] << 16);
                d3 = (unsigned int)tileu[cj * 8 + 6][w] | ((unsigned int)tileu[cj * 8 + 7][w] << 16);
                uint4 res; res.x = d0; res.y = d1; res.z = d2; res.w = d3;
                ((uint4*)featT)[((size_t)(b * Hh + h) * Ww + w) * 8 + cj] = res;
            }
        }
    } else {
        for (int e = (blk - 1280) * 256 + t; e < 147456 + 36864; e += WB * 256) {
            if (e < 147456) {
                // wofrag[kp(9)][ks(2)][mt(16)][lane(64)][j(8)]
                const int j    = e & 7;
                const int lane = (e >> 3) & 63;
                const int rest = e >> 9;
                const int mt = rest & 15;
                const int q  = rest >> 4;
                const int ks = q & 1;
                const int kp = q >> 1;
                const int co = mt * 16 + (lane & 15);
                const int ci = ks * 32 + (lane >> 4) * 8 + j;
                float v = (co < COFF) ? w_off[(size_t)co * 576 + ci * 9 + kp] : 0.f;
                wofrag[e] = f2bf(v);
            } else {
                // wfrag[ks(18)][mt(4)][lane(64)][j(8)], permuted K = g*72+kk*8+cg
                const int e2   = e - 147456;
                const int j    = e2 & 7;
                const int lane = (e2 >> 3) & 63;
                const int mt   = (e2 >> 9) & 3;
                const int ks   = e2 >> 11;
                const int m = mt * 16 + (lane & 15);
                const int k = ks * 32 + (lane >> 4) * 8 + j;
                const int g = k / 72, r = k % 72;
                const int kk = r >> 3, cg = r & 7;
                const int ci = g * 8 + cg;
                wfrag[e2] = f2bf(w_dcn[((size_t)m * CINc + ci) * 9 + kk]);
            }
        }
    }
}

// blend one dword-lane pair with packed bf16 convert (RNE, same as f2bf)
#define BLEND_J(out_, w00, w01, w10, w11, c00, c01, c10, c11) {            \
    float vl_ = (c00) * blo(w00) + (c01) * blo(w01)                        \
              + (c10) * blo(w10) + (c11) * blo(w11);                       \
    float vh_ = (c00) * bhi(w00) + (c01) * bhi(w01)                        \
              + (c10) * bhi(w10) + (c11) * bhi(w11);                       \
    asm("v_cvt_pk_bf16_f32 %0, %1, %2" : "=v"(out_) : "v"(vl_), "v"(vh_)); \
}

// ---------- Fused kernel (R1-proven version, NO setprio) --------------------
// block = 8x8 pixel tile, 256 threads (4 waves). 1600 blocks.
// NOTE: s_setprio around the MFMA clusters was tried (R3) and REGRESSED:
// it fences the scheduler, forces the q[6][4] gather batch to spill to
// scratch (+72 MB write, +36 MB fetch), 95.7 -> 139.6 us. Do not re-add.
__global__ __launch_bounds__(256, 3)
void dcnpack_fused(const unsigned short* __restrict__ featT,
                   const unsigned short* __restrict__ xG,
                   const unsigned short* __restrict__ wofrag,
                   const unsigned short* __restrict__ wfrag,
                   const float* __restrict__ b_off,
                   const float* __restrict__ b_dcn,
                   float* __restrict__ out) {
    __shared__ unsigned short smem[OFFS_SZ + UNION_SZ];
    unsigned short* offs = smem;                // [64 pix][OROW]: gk*3 + {dy,dx,mask}
    unsigned short* halo = smem + OFFS_SZ;      // [ry(10)][rx(10)][72] (conv phase)
    unsigned short* vbuf = smem + OFFS_SZ;      // [64 pix][VROW]     (dcn phase)

    const int b  = blockIdx.z;
    const int h0 = blockIdx.y * 8;
    const int w0 = blockIdx.x * 8;
    const int t  = threadIdx.x;
    const int wv   = t >> 6;
    const int lane = t & 63;
    const int n    = lane & 15;
    const int kg   = lane >> 4;

    // ---- stage halo: 100 pixels x 8 chunks of 8 bf16 ----
    for (int task = t; task < 800; task += 256) {
        const int pix = task >> 3, ch = task & 7;
        const int ry = pix / 10, rx = pix % 10;
        const int gh = h0 - 1 + ry, gw = w0 - 1 + rx;
        float4 v = make_float4(0.f, 0.f, 0.f, 0.f);
        if (gh >= 0 && gh < Hh && gw >= 0 && gw < Ww)
            v = *(const float4*)(featT + ((((size_t)b * Hh) + gh) * Ww + gw) * CINc + ch * 8);
        *(float4*)(halo + pix * 72 + ch * 8) = v;
    }
    __syncthreads();

    // ---- conv phase: M=256(pad of 216), N=64, K=576 ----
    const int bbase0 = (((n >> 3) * 10) + (n & 7)) * 72 + kg * 8;

    f32x4 cacc[4][4] = {};
    bf16x8 af[3][4];
    #pragma unroll
    for (int i = 0; i < 4; ++i)
        af[0][i] = *(const bf16x8*)(wofrag + (((size_t)0 * 16 + wv + 4 * i) * 64 + lane) * 8);
    #pragma unroll
    for (int i = 0; i < 4; ++i)
        af[1][i] = *(const bf16x8*)(wofrag + (((size_t)1 * 16 + wv + 4 * i) * 64 + lane) * 8);

    #pragma unroll
    for (int s = 0; s < 18; ++s) {
        if (s + 2 < 18) {
            #pragma unroll
            for (int i = 0; i < 4; ++i)
                af[(s + 2) % 3][i] = *(const bf16x8*)(wofrag +
                    (((size_t)(s + 2) * 16 + wv + 4 * i) * 64 + lane) * 8);
        }
        const int kp = s >> 1, ks = s & 1;
        const int ky = kp / 3, kx = kp % 3;
        #pragma unroll
        for (int nt = 0; nt < 4; ++nt) {
            const bf16x8 bfr = *(const bf16x8*)(halo + bbase0 + nt * 1440 +
                                                (ky * 10 + kx) * 72 + ks * 32);
            #pragma unroll
            for (int i = 0; i < 4; ++i)
                cacc[i][nt] = __builtin_amdgcn_mfma_f32_16x16x32_bf16(af[s % 3][i], bfr, cacc[i][nt], 0, 0, 0);
        }
    }

    // ---- conv epilogue: bias (+sigmoid for mask) -> offs LDS ----
    #pragma unroll
    for (int i = 0; i < 4; ++i) {
        const int mt = wv + 4 * i;
        #pragma unroll
        for (int r = 0; r < 4; ++r) {
            const int co = mt * 16 + kg * 4 + r;
            if (co < COFF) {
                const float bias = b_off[co];
                const int ismask = (co >= 144);
                const int gk = ismask ? (co - 144) : (co >> 1);
                const int type = ismask ? 2 : (co & 1);
                #pragma unroll
                for (int nt = 0; nt < 4; ++nt) {
                    const int p = nt * 16 + n;
                    float v = cacc[i][nt][r] + bias;
                    if (ismask) v = 1.f / (1.f + expf(-v));
                    offs[p * OROW + gk * 3 + type] = f2bf(v);
                }
            }
        }
    }
    __syncthreads();

    // ---- DCN: 3 K-windows of 192 (24 (g,k)-units); sample -> GEMM ----
    f32x4 dacc[4] = {};
    const int p_t = t & 63;
    const int h_s = h0 + (p_t >> 3);
    const int w_s = w0 + (p_t & 7);

    for (int c = 0; c < 3; ++c) {
        // -------- ISSUE phase: all offset reads + 24 gathers in flight ------
        float cf[6][4];
        uint4 q[6][4];
        #pragma unroll
        for (int it = 0; it < 6; ++it) {
            const int u = c * 24 + wv + it * 4;
            const int g = u / 9;
            const int k = u % 9;

            const float dy   = bf2f(offs[p_t * OROW + u * 3 + 0]);
            const float dx   = bf2f(offs[p_t * OROW + u * 3 + 1]);
            const float mask = bf2f(offs[p_t * OROW + u * 3 + 2]);

            const float py  = (float)h_s + (float)(k / 3 - 1) + dy;
            const float pxx = (float)w_s + (float)(k % 3 - 1) + dx;
            const float y0f = floorf(py), x0f = floorf(pxx);
            const float ly = py - y0f, lx = pxx - x0f;
            const int y0 = (int)y0f, x0i = (int)x0f;
            const int y1 = y0 + 1,  x1  = x0i + 1;

            const float vy0 = (y0 >= 0 && y0 < Hh) ? 1.f : 0.f;
            const float vy1 = (y1 >= 0 && y1 < Hh) ? 1.f : 0.f;
            const float vx0 = (x0i >= 0 && x0i < Ww) ? 1.f : 0.f;
            const float vx1 = (x1 >= 0 && x1 < Ww) ? 1.f : 0.f;

            cf[it][0] = (1.f - ly) * (1.f - lx) * vy0 * vx0 * mask;
            cf[it][1] = (1.f - ly) * lx         * vy0 * vx1 * mask;
            cf[it][2] = ly         * (1.f - lx) * vy1 * vx0 * mask;
            cf[it][3] = ly         * lx         * vy1 * vx1 * mask;

            const int y0c = min(max(y0, 0), Hh - 1), y1c = min(max(y1, 0), Hh - 1);
            const int x0c = min(max(x0i, 0), Ww - 1), x1c = min(max(x1, 0), Ww - 1);

            const unsigned short* xb = xG + ((size_t)b * Gg + g) * HW * 8;
            q[it][0] = *(const uint4*)(xb + ((size_t)y0c * Ww + x0c) * 8);
            q[it][1] = *(const uint4*)(xb + ((size_t)y0c * Ww + x1c) * 8);
            q[it][2] = *(const uint4*)(xb + ((size_t)y1c * Ww + x0c) * 8);
            q[it][3] = *(const uint4*)(xb + ((size_t)y1c * Ww + x1c) * 8);
        }

        // -------- BLEND phase: consume gathers, write vbuf ------------------
        #pragma unroll
        for (int it = 0; it < 6; ++it) {
            unsigned int rr0, rr1, rr2, rr3;
            BLEND_J(rr0, q[it][0].x, q[it][1].x, q[it][2].x, q[it][3].x,
                    cf[it][0], cf[it][1], cf[it][2], cf[it][3]);
            BLEND_J(rr1, q[it][0].y, q[it][1].y, q[it][2].y, q[it][3].y,
                    cf[it][0], cf[it][1], cf[it][2], cf[it][3]);
            BLEND_J(rr2, q[it][0].z, q[it][1].z, q[it][2].z, q[it][3].z,
                    cf[it][0], cf[it][1], cf[it][2], cf[it][3]);
            BLEND_J(rr3, q[it][0].w, q[it][1].w, q[it][2].w, q[it][3].w,
                    cf[it][0], cf[it][1], cf[it][2], cf[it][3]);
            uint4 res; res.x = rr0; res.y = rr1; res.z = rr2; res.w = rr3;
            *(uint4*)(vbuf + (size_t)p_t * VROW + (wv + it * 4) * 8) = res;
        }

        // prefetch this window's 6 A-fragments (global, L2) before the barrier
        bf16x8 afr[6];
        #pragma unroll
        for (int s = 0; s < 6; ++s)
            afr[s] = *(const bf16x8*)(wfrag + (((size_t)(c * 6 + s) * 4 + wv) * 64 + lane) * 8);

        __syncthreads();

        // GEMM over this window: 6 k-steps
        #pragma unroll
        for (int s = 0; s < 6; ++s) {
            #pragma unroll
            for (int nt = 0; nt < 4; ++nt) {
                const bf16x8 bfr = *(const bf16x8*)(vbuf + (nt * 16 + n) * VROW + s * 32 + kg * 8);
                dacc[nt] = __builtin_amdgcn_mfma_f32_16x16x32_bf16(afr[s], bfr, dacc[nt], 0, 0, 0);
            }
        }
        __syncthreads();
    }

    // ---- final epilogue: C/D col=lane&15 (pixel-in-ntile), row=kg*4+r (o) ----
    #pragma unroll
    for (int nt = 0; nt < 4; ++nt) {
        const int p = nt * 16 + n;
        const int h = h0 + (p >> 3);
        const int w = w0 + (p & 7);
        #pragma unroll
        for (int r = 0; r < 4; ++r) {
            const int o = wv * 16 + kg * 4 + r;
            out[(((size_t)b * CINc + o) * HW) + h * Ww + w] = dacc[nt][r] + b_dcn[o];
        }
    }
}

extern "C" void kernel_launch(void* const* d_in, const int* in_sizes, int n_in,
                              void* d_out, int out_size, void* d_ws, size_t ws_size,
                              hipStream_t stream) {
    const float* x     = (const float*)d_in[0];
    const float* feat  = (const float*)d_in[1];
    const float* w_off = (const float*)d_in[2];
    const float* b_off = (const float*)d_in[3];
    const float* w_dcn = (const float*)d_in[4];
    const float* b_dcn = (const float*)d_in[5];
    float* out = (float*)d_out;

    // ws layout (ushort elements): featT, xG, wofrag, wfrag  (~26.6 MB)
    unsigned short* featT  = (unsigned short*)d_ws;                // 6,553,600
    unsigned short* xG     = featT + (size_t)Bn * HW * CINc;       // 6,553,600
    unsigned short* wofrag = xG + (size_t)Bn * HW * CINc;          // 147,456
    unsigned short* wfrag  = wofrag + (size_t)147456;              // 36,864

    prep_kernel<<<dim3(1280 + WB), 256, 0, stream>>>(
        feat, x, w_off, w_dcn, featT, xG, wofrag, wfrag);
    dcnpack_fused<<<dim3(Ww / 8, Hh / 8, Bn), 256, 0, stream>>>(
        featT, xG, wofrag, wfrag, b_off, b_dcn, out);
}

// Round 5
// 184.710 us; speedup vs baseline: 1.1573x; 1.0076x over previous
//
#include <hip/hip_runtime.h>
#include <math.h>

#define Bn   4
#define CINc 64
#define Hh   160
#define Ww   160
#define Gg   8
#define HW   (Hh * Ww)      // 25600
#define COFF 216

#define OROW 220            // offs row stride (ushorts): conflict-free stagger
#define VROW 200            // vbuf row stride (ushorts): 16B-aligned rows
#define OFFS_SZ (64 * OROW)
#define UNION_SZ 12800
// fused smem = 26880 ushorts = 53760 B -> 3 blocks/CU

typedef short bf16x8 __attribute__((ext_vector_type(8)));
typedef float f32x4  __attribute__((ext_vector_type(4)));

static __device__ __forceinline__ unsigned short f2bf(float f) {
    unsigned int u = __float_as_uint(f);
    u = (u + 0x7fffu + ((u >> 16) & 1u)) >> 16;
    return (unsigned short)u;
}
static __device__ __forceinline__ float bf2f(unsigned short s) {
    return __uint_as_float(((unsigned int)s) << 16);
}
static __device__ __forceinline__ float blo(unsigned int u) {
    return __uint_as_float(u << 16);
}
static __device__ __forceinline__ float bhi(unsigned int u) {
    return __uint_as_float(u & 0xffff0000u);
}

// ---------- Prep v4: LDS-free streaming transpose + weight repacks ----------
// Structure ledger (residual = bench_total - fused):
//   v1.5 (f32 LDS tile):            ~96 us
//   v2   (bf16 LDS tile, u32 st):   ~55 us
//   v3   (bf16 tile, uint4 st):     ~90 us  <- 8-deep ds_read_u16 chains, REGRESSED
//   v4   (no LDS, gather-transpose): this round. Pure streaming, no barriers.
// blocks [0,800): feat -> featT[b][pix][64]   (thread = 4-pix quad x 8-ch chunk)
// blocks [800,1600): x -> xG[b][g][pix][8]    (thread = 4-pix quad x group)
// blocks [1600,1780): grid-stride weight repacks
__global__ __launch_bounds__(256)
void prep_kernel(const float* __restrict__ feat, const float* __restrict__ x,
                 const float* __restrict__ w_off, const float* __restrict__ w_dcn,
                 unsigned short* __restrict__ featT, unsigned short* __restrict__ xG,
                 unsigned short* __restrict__ wofrag, unsigned short* __restrict__ wfrag) {
    const int blk = blockIdx.x;
    const int t = threadIdx.x;
    if (blk < 800) {
        // featT: thread owns pixel-quad q (4 pixels), channel chunk cj (8 ch)
        const int b  = blk / 200;
        const int q  = (blk % 200) * 32 + (t >> 3);   // 0..6399
        const int cj = t & 7;
        const float* fb = feat + (size_t)b * CINc * HW;
        float4 v[8];
        #pragma unroll
        for (int m = 0; m < 8; ++m)      // 8 coalesced plane loads, all in flight
            v[m] = *(const float4*)(fb + (size_t)(cj * 8 + m) * HW + q * 4);
        uint4* dst = (uint4*)featT + ((size_t)b * HW + q * 4) * 8 + cj;
        #pragma unroll
        for (int k = 0; k < 4; ++k) {    // pixel k of the quad
            float e[8];
            #pragma unroll
            for (int m = 0; m < 8; ++m) {
                const float4 vv = v[m];
                e[m] = (k == 0) ? vv.x : (k == 1) ? vv.y : (k == 2) ? vv.z : vv.w;
            }
            unsigned int d0, d1, d2, d3;
            asm("v_cvt_pk_bf16_f32 %0, %1, %2" : "=v"(d0) : "v"(e[0]), "v"(e[1]));
            asm("v_cvt_pk_bf16_f32 %0, %1, %2" : "=v"(d1) : "v"(e[2]), "v"(e[3]));
            asm("v_cvt_pk_bf16_f32 %0, %1, %2" : "=v"(d2) : "v"(e[4]), "v"(e[5]));
            asm("v_cvt_pk_bf16_f32 %0, %1, %2" : "=v"(d3) : "v"(e[6]), "v"(e[7]));
            uint4 r4; r4.x = d0; r4.y = d1; r4.z = d2; r4.w = d3;
            dst[(size_t)k * 8] = r4;     // full-line tiling, no partial-line RMW
        }
    } else if (blk < 1600) {
        // xG: thread owns pixel-quad q for one (b,g); one uint4 = one pixel
        const int r  = blk - 800;
        const int bg = r / 25;                        // b*8+g
        const int q  = (r % 25) * 256 + t;            // 0..6399
        const float* xb = x + ((size_t)(bg >> 3) * CINc + (size_t)(bg & 7) * 8) * HW;
        float4 v[8];
        #pragma unroll
        for (int cg = 0; cg < 8; ++cg)   // 8 fully-contiguous 4KB plane loads
            v[cg] = *(const float4*)(xb + (size_t)cg * HW + q * 4);
        uint4* dst = (uint4*)xG + (size_t)bg * HW + q * 4;
        #pragma unroll
        for (int k = 0; k < 4; ++k) {
            float e[8];
            #pragma unroll
            for (int cg = 0; cg < 8; ++cg) {
                const float4 vv = v[cg];
                e[cg] = (k == 0) ? vv.x : (k == 1) ? vv.y : (k == 2) ? vv.z : vv.w;
            }
            unsigned int d0, d1, d2, d3;
            asm("v_cvt_pk_bf16_f32 %0, %1, %2" : "=v"(d0) : "v"(e[0]), "v"(e[1]));
            asm("v_cvt_pk_bf16_f32 %0, %1, %2" : "=v"(d1) : "v"(e[2]), "v"(e[3]));
            asm("v_cvt_pk_bf16_f32 %0, %1, %2" : "=v"(d2) : "v"(e[4]), "v"(e[5]));
            asm("v_cvt_pk_bf16_f32 %0, %1, %2" : "=v"(d3) : "v"(e[6]), "v"(e[7]));
            uint4 r4; r4.x = d0; r4.y = d1; r4.z = d2; r4.w = d3;
            dst[k] = r4;                 // 64B per lane across k -> full lines
        }
    } else {
        for (int e = (blk - 1600) * 256 + t; e < 147456 + 36864; e += 180 * 256) {
            if (e < 147456) {
                // wofrag[kp(9)][ks(2)][mt(16)][lane(64)][j(8)]
                const int j    = e & 7;
                const int lane = (e >> 3) & 63;
                const int rest = e >> 9;
                const int mt = rest & 15;
                const int q  = rest >> 4;
                const int ks = q & 1;
                const int kp = q >> 1;
                const int co = mt * 16 + (lane & 15);
                const int ci = ks * 32 + (lane >> 4) * 8 + j;
                float v = (co < COFF) ? w_off[(size_t)co * 576 + ci * 9 + kp] : 0.f;
                wofrag[e] = f2bf(v);
            } else {
                // wfrag[ks(18)][mt(4)][lane(64)][j(8)], permuted K = g*72+kk*8+cg
                const int e2   = e - 147456;
                const int j    = e2 & 7;
                const int lane = (e2 >> 3) & 63;
                const int mt   = (e2 >> 9) & 3;
                const int ks   = e2 >> 11;
                const int m = mt * 16 + (lane & 15);
                const int k = ks * 32 + (lane >> 4) * 8 + j;
                const int g = k / 72, r = k % 72;
                const int kk = r >> 3, cg = r & 7;
                const int ci = g * 8 + cg;
                wfrag[e2] = f2bf(w_dcn[((size_t)m * CINc + ci) * 9 + kk]);
            }
        }
    }
}

// blend one dword-lane pair with packed bf16 convert (RNE, same as f2bf)
#define BLEND_J(out_, w00, w01, w10, w11, c00, c01, c10, c11) {            \
    float vl_ = (c00) * blo(w00) + (c01) * blo(w01)                        \
              + (c10) * blo(w10) + (c11) * blo(w11);                       \
    float vh_ = (c00) * bhi(w00) + (c01) * bhi(w01)                        \
              + (c10) * bhi(w10) + (c11) * bhi(w11);                       \
    asm("v_cvt_pk_bf16_f32 %0, %1, %2" : "=v"(out_) : "v"(vl_), "v"(vh_)); \
}

// ---------- Fused kernel (R1-proven version, NO setprio) --------------------
// block = 8x8 pixel tile, 256 threads (4 waves). 1600 blocks.
// NOTE: s_setprio around the MFMA clusters was tried (R3) and REGRESSED:
// it fences the scheduler, forces the q[6][4] gather batch to spill to
// scratch (+72 MB write, +36 MB fetch), 95.7 -> 139.6 us. Do not re-add.
__global__ __launch_bounds__(256, 3)
void dcnpack_fused(const unsigned short* __restrict__ featT,
                   const unsigned short* __restrict__ xG,
                   const unsigned short* __restrict__ wofrag,
                   const unsigned short* __restrict__ wfrag,
                   const float* __restrict__ b_off,
                   const float* __restrict__ b_dcn,
                   float* __restrict__ out) {
    __shared__ unsigned short smem[OFFS_SZ + UNION_SZ];
    unsigned short* offs = smem;                // [64 pix][OROW]: gk*3 + {dy,dx,mask}
    unsigned short* halo = smem + OFFS_SZ;      // [ry(10)][rx(10)][72] (conv phase)
    unsigned short* vbuf = smem + OFFS_SZ;      // [64 pix][VROW]     (dcn phase)

    const int b  = blockIdx.z;
    const int h0 = blockIdx.y * 8;
    const int w0 = blockIdx.x * 8;
    const int t  = threadIdx.x;
    const int wv   = t >> 6;
    const int lane = t & 63;
    const int n    = lane & 15;
    const int kg   = lane >> 4;

    // ---- stage halo: 100 pixels x 8 chunks of 8 bf16 ----
    for (int task = t; task < 800; task += 256) {
        const int pix = task >> 3, ch = task & 7;
        const int ry = pix / 10, rx = pix % 10;
        const int gh = h0 - 1 + ry, gw = w0 - 1 + rx;
        float4 v = make_float4(0.f, 0.f, 0.f, 0.f);
        if (gh >= 0 && gh < Hh && gw >= 0 && gw < Ww)
            v = *(const float4*)(featT + ((((size_t)b * Hh) + gh) * Ww + gw) * CINc + ch * 8);
        *(float4*)(halo + pix * 72 + ch * 8) = v;
    }
    __syncthreads();

    // ---- conv phase: M=256(pad of 216), N=64, K=576 ----
    const int bbase0 = (((n >> 3) * 10) + (n & 7)) * 72 + kg * 8;

    f32x4 cacc[4][4] = {};
    bf16x8 af[3][4];
    #pragma unroll
    for (int i = 0; i < 4; ++i)
        af[0][i] = *(const bf16x8*)(wofrag + (((size_t)0 * 16 + wv + 4 * i) * 64 + lane) * 8);
    #pragma unroll
    for (int i = 0; i < 4; ++i)
        af[1][i] = *(const bf16x8*)(wofrag + (((size_t)1 * 16 + wv + 4 * i) * 64 + lane) * 8);

    #pragma unroll
    for (int s = 0; s < 18; ++s) {
        if (s + 2 < 18) {
            #pragma unroll
            for (int i = 0; i < 4; ++i)
                af[(s + 2) % 3][i] = *(const bf16x8*)(wofrag +
                    (((size_t)(s + 2) * 16 + wv + 4 * i) * 64 + lane) * 8);
        }
        const int kp = s >> 1, ks = s & 1;
        const int ky = kp / 3, kx = kp % 3;
        #pragma unroll
        for (int nt = 0; nt < 4; ++nt) {
            const bf16x8 bfr = *(const bf16x8*)(halo + bbase0 + nt * 1440 +
                                                (ky * 10 + kx) * 72 + ks * 32);
            #pragma unroll
            for (int i = 0; i < 4; ++i)
                cacc[i][nt] = __builtin_amdgcn_mfma_f32_16x16x32_bf16(af[s % 3][i], bfr, cacc[i][nt], 0, 0, 0);
        }
    }

    // ---- conv epilogue: bias (+sigmoid for mask) -> offs LDS ----
    #pragma unroll
    for (int i = 0; i < 4; ++i) {
        const int mt = wv + 4 * i;
        #pragma unroll
        for (int r = 0; r < 4; ++r) {
            const int co = mt * 16 + kg * 4 + r;
            if (co < COFF) {
                const float bias = b_off[co];
                const int ismask = (co >= 144);
                const int gk = ismask ? (co - 144) : (co >> 1);
                const int type = ismask ? 2 : (co & 1);
                #pragma unroll
                for (int nt = 0; nt < 4; ++nt) {
                    const int p = nt * 16 + n;
                    float v = cacc[i][nt][r] + bias;
                    if (ismask) v = 1.f / (1.f + expf(-v));
                    offs[p * OROW + gk * 3 + type] = f2bf(v);
                }
            }
        }
    }
    __syncthreads();

    // ---- DCN: 3 K-windows of 192 (24 (g,k)-units); sample -> GEMM ----
    f32x4 dacc[4] = {};
    const int p_t = t & 63;
    const int h_s = h0 + (p_t >> 3);
    const int w_s = w0 + (p_t & 7);

    for (int c = 0; c < 3; ++c) {
        // -------- ISSUE phase: all offset reads + 24 gathers in flight ------
        float cf[6][4];
        uint4 q[6][4];
        #pragma unroll
        for (int it = 0; it < 6; ++it) {
            const int u = c * 24 + wv + it * 4;
            const int g = u / 9;
            const int k = u % 9;

            const float dy   = bf2f(offs[p_t * OROW + u * 3 + 0]);
            const float dx   = bf2f(offs[p_t * OROW + u * 3 + 1]);
            const float mask = bf2f(offs[p_t * OROW + u * 3 + 2]);

            const float py  = (float)h_s + (float)(k / 3 - 1) + dy;
            const float pxx = (float)w_s + (float)(k % 3 - 1) + dx;
            const float y0f = floorf(py), x0f = floorf(pxx);
            const float ly = py - y0f, lx = pxx - x0f;
            const int y0 = (int)y0f, x0i = (int)x0f;
            const int y1 = y0 + 1,  x1  = x0i + 1;

            const float vy0 = (y0 >= 0 && y0 < Hh) ? 1.f : 0.f;
            const float vy1 = (y1 >= 0 && y1 < Hh) ? 1.f : 0.f;
            const float vx0 = (x0i >= 0 && x0i < Ww) ? 1.f : 0.f;
            const float vx1 = (x1 >= 0 && x1 < Ww) ? 1.f : 0.f;

            cf[it][0] = (1.f - ly) * (1.f - lx) * vy0 * vx0 * mask;
            cf[it][1] = (1.f - ly) * lx         * vy0 * vx1 * mask;
            cf[it][2] = ly         * (1.f - lx) * vy1 * vx0 * mask;
            cf[it][3] = ly         * lx         * vy1 * vx1 * mask;

            const int y0c = min(max(y0, 0), Hh - 1), y1c = min(max(y1, 0), Hh - 1);
            const int x0c = min(max(x0i, 0), Ww - 1), x1c = min(max(x1, 0), Ww - 1);

            const unsigned short* xb = xG + ((size_t)b * Gg + g) * HW * 8;
            q[it][0] = *(const uint4*)(xb + ((size_t)y0c * Ww + x0c) * 8);
            q[it][1] = *(const uint4*)(xb + ((size_t)y0c * Ww + x1c) * 8);
            q[it][2] = *(const uint4*)(xb + ((size_t)y1c * Ww + x0c) * 8);
            q[it][3] = *(const uint4*)(xb + ((size_t)y1c * Ww + x1c) * 8);
        }

        // -------- BLEND phase: consume gathers, write vbuf ------------------
        #pragma unroll
        for (int it = 0; it < 6; ++it) {
            unsigned int rr0, rr1, rr2, rr3;
            BLEND_J(rr0, q[it][0].x, q[it][1].x, q[it][2].x, q[it][3].x,
                    cf[it][0], cf[it][1], cf[it][2], cf[it][3]);
            BLEND_J(rr1, q[it][0].y, q[it][1].y, q[it][2].y, q[it][3].y,
                    cf[it][0], cf[it][1], cf[it][2], cf[it][3]);
            BLEND_J(rr2, q[it][0].z, q[it][1].z, q[it][2].z, q[it][3].z,
                    cf[it][0], cf[it][1], cf[it][2], cf[it][3]);
            BLEND_J(rr3, q[it][0].w, q[it][1].w, q[it][2].w, q[it][3].w,
                    cf[it][0], cf[it][1], cf[it][2], cf[it][3]);
            uint4 res; res.x = rr0; res.y = rr1; res.z = rr2; res.w = rr3;
            *(uint4*)(vbuf + (size_t)p_t * VROW + (wv + it * 4) * 8) = res;
        }

        // prefetch this window's 6 A-fragments (global, L2) before the barrier
        bf16x8 afr[6];
        #pragma unroll
        for (int s = 0; s < 6; ++s)
            afr[s] = *(const bf16x8*)(wfrag + (((size_t)(c * 6 + s) * 4 + wv) * 64 + lane) * 8);

        __syncthreads();

        // GEMM over this window: 6 k-steps
        #pragma unroll
        for (int s = 0; s < 6; ++s) {
            #pragma unroll
            for (int nt = 0; nt < 4; ++nt) {
                const bf16x8 bfr = *(const bf16x8*)(vbuf + (nt * 16 + n) * VROW + s * 32 + kg * 8);
                dacc[nt] = __builtin_amdgcn_mfma_f32_16x16x32_bf16(afr[s], bfr, dacc[nt], 0, 0, 0);
            }
        }
        __syncthreads();
    }

    // ---- final epilogue: C/D col=lane&15 (pixel-in-ntile), row=kg*4+r (o) ----
    #pragma unroll
    for (int nt = 0; nt < 4; ++nt) {
        const int p = nt * 16 + n;
        const int h = h0 + (p >> 3);
        const int w = w0 + (p & 7);
        #pragma unroll
        for (int r = 0; r < 4; ++r) {
            const int o = wv * 16 + kg * 4 + r;
            out[(((size_t)b * CINc + o) * HW) + h * Ww + w] = dacc[nt][r] + b_dcn[o];
        }
    }
}

extern "C" void kernel_launch(void* const* d_in, const int* in_sizes, int n_in,
                              void* d_out, int out_size, void* d_ws, size_t ws_size,
                              hipStream_t stream) {
    const float* x     = (const float*)d_in[0];
    const float* feat  = (const float*)d_in[1];
    const float* w_off = (const float*)d_in[2];
    const float* b_off = (const float*)d_in[3];
    const float* w_dcn = (const float*)d_in[4];
    const float* b_dcn = (const float*)d_in[5];
    float* out = (float*)d_out;

    // ws layout (ushort elements): featT, xG, wofrag, wfrag  (~26.6 MB)
    unsigned short* featT  = (unsigned short*)d_ws;                // 6,553,600
    unsigned short* xG     = featT + (size_t)Bn * HW * CINc;       // 6,553,600
    unsigned short* wofrag = xG + (size_t)Bn * HW * CINc;          // 147,456
    unsigned short* wfrag  = wofrag + (size_t)147456;              // 36,864

    prep_kernel<<<dim3(1780), 256, 0, stream>>>(
        feat, x, w_off, w_dcn, featT, xG, wofrag, wfrag);
    dcnpack_fused<<<dim3(Ww / 8, Hh / 8, Bn), 256, 0, stream>>>(
        featT, xG, wofrag, wfrag, b_off, b_dcn, out);
}